// Round 1
// baseline (713.206 us; speedup 1.0000x reference)
//
#include <hip/hip_runtime.h>
#include <hip/hip_bf16.h>
#include <stdint.h>

// Problem constants
#define NN 32768
#define KNBR 32
#define FDIM 4
#define WDIM 256

typedef __attribute__((ext_vector_type(8))) short short8;
typedef __attribute__((ext_vector_type(4))) float f32x4;

__device__ __forceinline__ unsigned int f2bf(float x) {
    union { float f; unsigned int u; } c; c.f = x;
    return (c.u + 0x7FFFu + ((c.u >> 16) & 1u)) >> 16;
}
__device__ __forceinline__ unsigned int pk2(float a, float b) {
    return f2bf(a) | (f2bf(b) << 16);
}
__device__ __forceinline__ float silu_f(float x) {
    return x / (1.0f + __expf(-x));
}

// ---------------------------------------------------------------------------
// Kernel 1: convert W_f2, W_nb, W_c (f32 row-major [256][256]) into bf16
// MFMA B-fragment layout: frag q = (kt*16 + nt)*64 + lane holds
// B[k = kt*32 + (lane>>4)*8 + i][col = nt*16 + (lane&15)], i=0..7, 16B/frag.
// ws layout: [0,8192) frags = W_f2, [8192,16384) = W_nb, [16384,24576) = W_c.
// ---------------------------------------------------------------------------
__global__ void prep_weights(const float* __restrict__ Wf2,
                             const float* __restrict__ Wnb,
                             const float* __restrict__ Wc,
                             uint4* __restrict__ ws_out) {
    int t = blockIdx.x * 256 + threadIdx.x;   // 0..24575
    int w = t >> 13;
    int q = t & 8191;
    int kt = q >> 10;
    int nt = (q >> 6) & 15;
    int lane = q & 63;
    int k0 = kt * 32 + ((lane >> 4) << 3);
    int col = nt * 16 + (lane & 15);
    const float* src = (w == 0) ? Wf2 : (w == 1) ? Wnb : Wc;
    const float* p = src + (size_t)k0 * 256 + col;
    uint4 o;
    o.x = pk2(p[0],        p[256]);
    o.y = pk2(p[512],      p[768]);
    o.z = pk2(p[1024],     p[1280]);
    o.w = pk2(p[1536],     p[1792]);
    ws_out[t] = o;
}

// ---------------------------------------------------------------------------
// Kernel 2: fused edge pipeline. Per block: 4 nodes = 128 edge rows.
//  f = silu(diff @ Wf1 + b1)            [128,256]  (bf16, LDS, A-frag layout)
//  Phi = f @ Wf2 ; H = E @ Wnb          (dual-accumulator MFMA GEMM)
//  msg[node] = sum_rows (Phi+b2) * (H+bnb)  -> written to msg_out (= d_out)
// 512 threads = 8 waves (2 M x 4 N), per-wave 64x64 output tile per GEMM.
// ---------------------------------------------------------------------------
__global__ __launch_bounds__(512) void msg_kernel(
        const float* __restrict__ nbr,    // h_neighbors [N*K, 256]
        const float* __restrict__ diff,   // differences [N*K, 4]
        const float* __restrict__ Wf1,    // [4,256]
        const float* __restrict__ b1,     // [256]
        const float* __restrict__ b2,     // b_f2 [256]
        const float* __restrict__ bnb,    // b_nb [256]
        const uint4* __restrict__ wf2_g,  // frag bf16, 8192 uint4
        const uint4* __restrict__ wnb_g,  // frag bf16, 8192 uint4
        float* __restrict__ msg_out)      // [N,256] f32
{
    __shared__ unsigned short f_frag[8 * 8 * 64 * 8];   // 64KB  (8 mt x 8 ktf)
    __shared__ unsigned short e_frag[8 * 2 * 64 * 8];   // 16KB  (8 mt x 2 kti)
    __shared__ unsigned short wnb_s[2 * 16 * 64 * 8];   // 32KB  (2 kti x 16 nt)
    __shared__ unsigned short wf2_s[2 * 16 * 64 * 8];   // 32KB
    __shared__ float wf1_s[4 * 256];                    // 4KB
    __shared__ float b1_s[256];                         // 1KB

    const int tid  = threadIdx.x;
    const int lane = tid & 63;
    const int wid  = tid >> 6;
    const int wm   = wid >> 2;    // 0..1  (row half)
    const int wn   = wid & 3;     // 0..3  (col quarter)
    const int eblk = blockIdx.x * 128;

    // ---- stage Wf1 + b1 ----
    for (int i = tid; i < 1024; i += 512) wf1_s[i] = Wf1[i];
    if (tid < 256) b1_s[tid] = b1[tid];
    __syncthreads();

    // ---- phase 1: f = silu(diff @ Wf1 + b1), write A-frags ----
    uint4* ff4 = (uint4*)f_frag;
    #pragma unroll
    for (int j = 0; j < 8; ++j) {
        int q   = tid + j * 512;          // 0..4095
        int lq  = q & 63;
        int ktf = (q >> 6) & 7;
        int mt  = q >> 9;
        int row = mt * 16 + (lq & 15);
        int k0  = ktf * 32 + ((lq >> 4) << 3);
        const float4 d4 = *(const float4*)(diff + (size_t)(eblk + row) * 4);
        float vals[8];
        #pragma unroll
        for (int i = 0; i < 8; ++i) {
            int k = k0 + i;
            float v = b1_s[k] + d4.x * wf1_s[k]       + d4.y * wf1_s[256 + k]
                              + d4.z * wf1_s[512 + k] + d4.w * wf1_s[768 + k];
            vals[i] = silu_f(v);
        }
        uint4 o;
        o.x = pk2(vals[0], vals[1]); o.y = pk2(vals[2], vals[3]);
        o.z = pk2(vals[4], vals[5]); o.w = pk2(vals[6], vals[7]);
        ff4[q] = o;
    }
    __syncthreads();

    // ---- K-loop ----
    f32x4 accH[4][4], accP[4][4];
    #pragma unroll
    for (int mt = 0; mt < 4; ++mt)
        #pragma unroll
        for (int nt = 0; nt < 4; ++nt) {
            accH[mt][nt] = (f32x4){0.f, 0.f, 0.f, 0.f};
            accP[mt][nt] = (f32x4){0.f, 0.f, 0.f, 0.f};
        }

    uint4* ef4 = (uint4*)e_frag;
    for (int kt2 = 0; kt2 < 4; ++kt2) {
        // stage E tile: 128 rows x 64 k (f32 -> bf16 frags)
        {
            int row = tid >> 2, quarter = tid & 3;
            const float* src = nbr + (size_t)(eblk + row) * 256 + kt2 * 64 + quarter * 16;
            float4 v0 = *(const float4*)(src + 0);
            float4 v1 = *(const float4*)(src + 4);
            float4 v2 = *(const float4*)(src + 8);
            float4 v3 = *(const float4*)(src + 12);
            uint4 p0, p1;
            p0.x = pk2(v0.x, v0.y); p0.y = pk2(v0.z, v0.w);
            p0.z = pk2(v1.x, v1.y); p0.w = pk2(v1.z, v1.w);
            p1.x = pk2(v2.x, v2.y); p1.y = pk2(v2.z, v2.w);
            p1.z = pk2(v3.x, v3.y); p1.w = pk2(v3.z, v3.w);
            int mt = row >> 4, kti = quarter >> 1, fr = row & 15;
            int g0 = (quarter & 1) * 2;
            ef4[(mt * 2 + kti) * 64 + g0 * 16 + fr]       = p0;
            ef4[(mt * 2 + kti) * 64 + (g0 + 1) * 16 + fr] = p1;
        }
        // stage weight tiles (linear 16B copies)
        {
            const uint4* srcn = wnb_g + kt2 * 2048;
            const uint4* srcf = wf2_g + kt2 * 2048;
            uint4* dn = (uint4*)wnb_s;
            uint4* df = (uint4*)wf2_s;
            #pragma unroll
            for (int j = 0; j < 4; ++j) {
                dn[j * 512 + tid] = srcn[j * 512 + tid];
                df[j * 512 + tid] = srcf[j * 512 + tid];
            }
        }
        __syncthreads();

        #pragma unroll
        for (int kti = 0; kti < 2; ++kti) {
            short8 bN[4], bF[4];
            #pragma unroll
            for (int nt = 0; nt < 4; ++nt) {
                int ntg = wn * 4 + nt;
                bN[nt] = *(const short8*)&wnb_s[((kti * 16 + ntg) * 64 + lane) * 8];
                bF[nt] = *(const short8*)&wf2_s[((kti * 16 + ntg) * 64 + lane) * 8];
            }
            #pragma unroll
            for (int mt = 0; mt < 4; ++mt) {
                int mtg = wm * 4 + mt;
                short8 aE = *(const short8*)&e_frag[((mtg * 2 + kti) * 64 + lane) * 8];
                short8 aF = *(const short8*)&f_frag[((mtg * 8 + kt2 * 2 + kti) * 64 + lane) * 8];
                #pragma unroll
                for (int nt = 0; nt < 4; ++nt) {
                    accH[mt][nt] = __builtin_amdgcn_mfma_f32_16x16x32_bf16(aE, bN[nt], accH[mt][nt], 0, 0, 0);
                    accP[mt][nt] = __builtin_amdgcn_mfma_f32_16x16x32_bf16(aF, bF[nt], accP[mt][nt], 0, 0, 0);
                }
            }
        }
        __syncthreads();
    }

    // ---- epilogue: gate + per-node row reduction ----
    // acc row (local) = (wm*4+mt)*16 + (lane>>4)*4 + r ; col = wn*64 + nt*16 + (lane&15)
    #pragma unroll
    for (int nd = 0; nd < 2; ++nd) {
        int node = blockIdx.x * 4 + wm * 2 + nd;
        #pragma unroll
        for (int nt = 0; nt < 4; ++nt) {
            int col = wn * 64 + nt * 16 + (lane & 15);
            float vb2 = b2[col];
            float vbn = bnb[col];
            float s = 0.f;
            #pragma unroll
            for (int m2 = 0; m2 < 2; ++m2) {
                int mt = nd * 2 + m2;
                #pragma unroll
                for (int r = 0; r < 4; ++r)
                    s += (accP[mt][nt][r] + vb2) * (accH[mt][nt][r] + vbn);
            }
            s += __shfl_xor(s, 16);
            s += __shfl_xor(s, 32);
            if (lane < 16) msg_out[(size_t)node * 256 + col] = s;
        }
    }
}

// ---------------------------------------------------------------------------
// Kernel 3: out = silu(h_center @ Wc + bc + msg), msg lives in `out` already.
// 256 threads = 4 waves (col quarters), 64 rows per block.
// ---------------------------------------------------------------------------
__global__ __launch_bounds__(256) void out_kernel(
        const float* __restrict__ hc,     // [N,256]
        const float* __restrict__ bc,     // [256]
        const uint4* __restrict__ wc_g,   // frag bf16, 8192 uint4
        float* __restrict__ out)          // [N,256], contains msg on entry
{
    __shared__ unsigned short a_s[4 * 2 * 64 * 8];    // 8KB
    __shared__ unsigned short wc_s[2 * 16 * 64 * 8];  // 32KB

    const int tid  = threadIdx.x;
    const int lane = tid & 63;
    const int wn   = tid >> 6;        // 0..3
    const int rblk = blockIdx.x * 64;

    f32x4 acc[4][4];
    #pragma unroll
    for (int mt = 0; mt < 4; ++mt)
        #pragma unroll
        for (int nt = 0; nt < 4; ++nt)
            acc[mt][nt] = (f32x4){0.f, 0.f, 0.f, 0.f};

    uint4* af4 = (uint4*)a_s;
    for (int kt2 = 0; kt2 < 4; ++kt2) {
        {
            int row = tid >> 2, quarter = tid & 3;
            const float* src = hc + (size_t)(rblk + row) * 256 + kt2 * 64 + quarter * 16;
            float4 v0 = *(const float4*)(src + 0);
            float4 v1 = *(const float4*)(src + 4);
            float4 v2 = *(const float4*)(src + 8);
            float4 v3 = *(const float4*)(src + 12);
            uint4 p0, p1;
            p0.x = pk2(v0.x, v0.y); p0.y = pk2(v0.z, v0.w);
            p0.z = pk2(v1.x, v1.y); p0.w = pk2(v1.z, v1.w);
            p1.x = pk2(v2.x, v2.y); p1.y = pk2(v2.z, v2.w);
            p1.z = pk2(v3.x, v3.y); p1.w = pk2(v3.z, v3.w);
            int mt = row >> 4, kti = quarter >> 1, fr = row & 15;
            int g0 = (quarter & 1) * 2;
            af4[(mt * 2 + kti) * 64 + g0 * 16 + fr]       = p0;
            af4[(mt * 2 + kti) * 64 + (g0 + 1) * 16 + fr] = p1;
            const uint4* srcw = wc_g + kt2 * 2048;
            uint4* dw = (uint4*)wc_s;
            #pragma unroll
            for (int j = 0; j < 8; ++j)
                dw[j * 256 + tid] = srcw[j * 256 + tid];
        }
        __syncthreads();
        #pragma unroll
        for (int kti = 0; kti < 2; ++kti) {
            short8 b[4];
            #pragma unroll
            for (int nt = 0; nt < 4; ++nt)
                b[nt] = *(const short8*)&wc_s[((kti * 16 + wn * 4 + nt) * 64 + lane) * 8];
            #pragma unroll
            for (int mt = 0; mt < 4; ++mt) {
                short8 a = *(const short8*)&a_s[((mt * 2 + kti) * 64 + lane) * 8];
                #pragma unroll
                for (int nt = 0; nt < 4; ++nt)
                    acc[mt][nt] = __builtin_amdgcn_mfma_f32_16x16x32_bf16(a, b[nt], acc[mt][nt], 0, 0, 0);
            }
        }
        __syncthreads();
    }

    #pragma unroll
    for (int mt = 0; mt < 4; ++mt)
        #pragma unroll
        for (int nt = 0; nt < 4; ++nt)
            #pragma unroll
            for (int r = 0; r < 4; ++r) {
                int grow = rblk + mt * 16 + ((lane >> 4) << 2) + r;
                int col  = wn * 64 + nt * 16 + (lane & 15);
                size_t idx = (size_t)grow * 256 + col;
                float v = acc[mt][nt][r] + bc[col] + out[idx];
                out[idx] = silu_f(v);
            }
}

// ---------------------------------------------------------------------------
extern "C" void kernel_launch(void* const* d_in, const int* in_sizes, int n_in,
                              void* d_out, int out_size, void* d_ws, size_t ws_size,
                              hipStream_t stream) {
    const float* h_center    = (const float*)d_in[0];
    const float* h_neighbors = (const float*)d_in[1];
    const float* differences = (const float*)d_in[2];
    const float* W_f1        = (const float*)d_in[3];
    const float* b_f1        = (const float*)d_in[4];
    const float* W_f2        = (const float*)d_in[5];
    const float* b_f2        = (const float*)d_in[6];
    const float* W_nb        = (const float*)d_in[7];
    const float* b_nb        = (const float*)d_in[8];
    const float* W_c         = (const float*)d_in[9];
    const float* b_c         = (const float*)d_in[10];
    float* out = (float*)d_out;

    uint4* ws4 = (uint4*)d_ws;            // 24576 * 16B = 384KB of scratch
    const uint4* wf2_ws = ws4;            // [0, 8192)
    const uint4* wnb_ws = ws4 + 8192;     // [8192, 16384)
    const uint4* wc_ws  = ws4 + 16384;    // [16384, 24576)

    prep_weights<<<96, 256, 0, stream>>>(W_f2, W_nb, W_c, ws4);
    msg_kernel<<<NN / 4, 512, 0, stream>>>(h_neighbors, differences, W_f1, b_f1,
                                           b_f2, b_nb, wf2_ws, wnb_ws, out);
    out_kernel<<<NN / 64, 256, 0, stream>>>(h_center, b_c, wc_ws, out);
}

// Round 2
// 639.972 us; speedup vs baseline: 1.1144x; 1.1144x over previous
//
#include <hip/hip_runtime.h>
#include <hip/hip_bf16.h>
#include <stdint.h>

// Problem constants
#define NN 32768
#define KNBR 32
#define FDIM 4
#define WDIM 256

typedef __attribute__((ext_vector_type(8))) short short8;
typedef __attribute__((ext_vector_type(4))) float f32x4;

__device__ __forceinline__ unsigned int f2bf(float x) {
    union { float f; unsigned int u; } c; c.f = x;
    return (c.u + 0x7FFFu + ((c.u >> 16) & 1u)) >> 16;
}
__device__ __forceinline__ unsigned int pk2(float a, float b) {
    return f2bf(a) | (f2bf(b) << 16);
}
__device__ __forceinline__ float silu_f(float x) {
    return x / (1.0f + __expf(-x));
}

// ---------------------------------------------------------------------------
// Kernel 1: convert W_f2, W_nb, W_c (f32 row-major [256][256]) into bf16
// MFMA B-fragment layout: frag q = (kt*16 + nt)*64 + lane holds
// B[k = kt*32 + (lane>>4)*8 + i][col = nt*16 + (lane&15)], i=0..7, 16B/frag.
// ws layout: [0,8192) frags = W_f2, [8192,16384) = W_nb, [16384,24576) = W_c.
// ---------------------------------------------------------------------------
__global__ void prep_weights(const float* __restrict__ Wf2,
                             const float* __restrict__ Wnb,
                             const float* __restrict__ Wc,
                             uint4* __restrict__ ws_out) {
    int t = blockIdx.x * 256 + threadIdx.x;   // 0..24575
    int w = t >> 13;
    int q = t & 8191;
    int kt = q >> 10;
    int nt = (q >> 6) & 15;
    int lane = q & 63;
    int k0 = kt * 32 + ((lane >> 4) << 3);
    int col = nt * 16 + (lane & 15);
    const float* src = (w == 0) ? Wf2 : (w == 1) ? Wnb : Wc;
    const float* p = src + (size_t)k0 * 256 + col;
    uint4 o;
    o.x = pk2(p[0],        p[256]);
    o.y = pk2(p[512],      p[768]);
    o.z = pk2(p[1024],     p[1280]);
    o.w = pk2(p[1536],     p[1792]);
    ws_out[t] = o;
}

// ---------------------------------------------------------------------------
// Kernel 2: fused edge pipeline, two-pass per block to halve acc registers.
// Block = 64 edge rows (2 nodes) x 256 cols, 512 threads = 8 waves.
// Wave w owns col slice [w*32, w*32+32): tile 64x32 -> 8 C-frags = 32 acc f32.
// Phase A: Phi = silu(diff@Wf1+b1) @ Wf2 ; (Phi+b2)->bf16 -> phi_s (wave-local)
// Phase B: H = E @ Wnb (same acc regs)
// Epilogue: msg[node,col] = sum_rows phi * (H+bnb), shfl-reduce, store.
// ---------------------------------------------------------------------------
__global__ __launch_bounds__(512, 4) void msg_kernel(
        const float* __restrict__ nbr,    // h_neighbors [N*K, 256]
        const float* __restrict__ diff,   // differences [N*K, 4]
        const float* __restrict__ Wf1,    // [4,256]
        const float* __restrict__ b1,     // [256]
        const float* __restrict__ b2,     // b_f2 [256]
        const float* __restrict__ bnb,    // b_nb [256]
        const uint4* __restrict__ wf2_g,  // frag bf16, 8192 uint4
        const uint4* __restrict__ wnb_g,  // frag bf16, 8192 uint4
        float* __restrict__ msg_out)      // [N,256] f32
{
    __shared__ unsigned short stage_s[8 * 64 * 8];   // 8KB  A-frags (f or E)
    __shared__ unsigned short w_s[2 * 16 * 64 * 8];  // 32KB one weight, 2 kti
    __shared__ unsigned int   phi_s[8192];           // 32KB packed (Phi+b2)
    __shared__ float wf1_s[1024];                    // 4KB
    __shared__ float b1_s[256];                      // 1KB

    const int tid  = threadIdx.x;
    const int lane = tid & 63;
    const int wid  = tid >> 6;           // 0..7 col slice
    const int eblk = blockIdx.x * 64;

    // per-thread staging coords: this thread fills A-frag group g = wid
    // (mt = g>>1, kti = g&1), element (row, klo..klo+8) of the 64x64 k-tile.
    const int g    = wid;
    const int row  = ((g >> 1) << 4) + (lane & 15);       // 0..63
    const int klo  = ((g & 1) << 5) + ((lane >> 4) << 3); // 0..56

    for (int i = tid; i < 1024; i += 512) wf1_s[i] = Wf1[i];
    if (tid < 256) b1_s[tid] = b1[tid];
    const float4 d4 = *(const float4*)(diff + (size_t)(eblk + row) * 4);

    uint4* stage4 = (uint4*)stage_s;
    uint4* ws4l   = (uint4*)w_s;

    f32x4 acc[4][2];
    #pragma unroll
    for (int mt = 0; mt < 4; ++mt) {
        acc[mt][0] = (f32x4){0.f, 0.f, 0.f, 0.f};
        acc[mt][1] = (f32x4){0.f, 0.f, 0.f, 0.f};
    }

    __syncthreads();   // wf1_s / b1_s ready

    // =================== PHASE A: Phi = f @ Wf2 ===================
    for (int kt2 = 0; kt2 < 4; ++kt2) {
        // stage f frag (8 silu values -> 1 uint4)
        {
            const int kb = kt2 * 64 + klo;
            float vals[8];
            #pragma unroll
            for (int i = 0; i < 8; ++i) {
                int k = kb + i;
                float v = b1_s[k] + d4.x * wf1_s[k]       + d4.y * wf1_s[256 + k]
                                  + d4.z * wf1_s[512 + k] + d4.w * wf1_s[768 + k];
                vals[i] = silu_f(v);
            }
            uint4 o;
            o.x = pk2(vals[0], vals[1]); o.y = pk2(vals[2], vals[3]);
            o.z = pk2(vals[4], vals[5]); o.w = pk2(vals[6], vals[7]);
            stage4[tid] = o;
        }
        // stage Wf2 tile (both kti, 32KB linear copy)
        {
            const uint4* srcw = wf2_g + (size_t)kt2 * 2048;
            ws4l[tid]        = srcw[tid];
            ws4l[512 + tid]  = srcw[512 + tid];
            ws4l[1024 + tid] = srcw[1024 + tid];
            ws4l[1536 + tid] = srcw[1536 + tid];
        }
        __syncthreads();
        #pragma unroll
        for (int kti = 0; kti < 2; ++kti) {
            short8 bA = *(const short8*)&w_s[((kti * 16 + wid * 2 + 0) * 64 + lane) * 8];
            short8 bB = *(const short8*)&w_s[((kti * 16 + wid * 2 + 1) * 64 + lane) * 8];
            #pragma unroll
            for (int mt = 0; mt < 4; ++mt) {
                short8 a = *(const short8*)&stage_s[((mt * 2 + kti) * 64 + lane) * 8];
                acc[mt][0] = __builtin_amdgcn_mfma_f32_16x16x32_bf16(a, bA, acc[mt][0], 0, 0, 0);
                acc[mt][1] = __builtin_amdgcn_mfma_f32_16x16x32_bf16(a, bB, acc[mt][1], 0, 0, 0);
            }
        }
        __syncthreads();
    }

    // pack (Phi + b2) -> bf16 into wave-local phi_s region; re-zero acc
    #pragma unroll
    for (int nt = 0; nt < 2; ++nt) {
        float vb2 = b2[wid * 32 + nt * 16 + (lane & 15)];
        #pragma unroll
        for (int mt = 0; mt < 4; ++mt) {
            int base = (((wid * 2 + nt) * 4 + mt) * 64 + lane) * 2;
            phi_s[base]     = pk2(acc[mt][nt][0] + vb2, acc[mt][nt][1] + vb2);
            phi_s[base + 1] = pk2(acc[mt][nt][2] + vb2, acc[mt][nt][3] + vb2);
            acc[mt][nt] = (f32x4){0.f, 0.f, 0.f, 0.f};
        }
    }
    // no barrier needed: phi_s region is written and read by the same wave;
    // stage_s / w_s reuse below is protected by the loop's end barrier above.

    // =================== PHASE B: H = E @ Wnb ===================
    for (int kt2 = 0; kt2 < 4; ++kt2) {
        // stage E frag (8 f32 -> bf16 -> 1 uint4)
        {
            const float* src = nbr + (size_t)(eblk + row) * 256 + kt2 * 64 + klo;
            float4 v0 = *(const float4*)(src);
            float4 v1 = *(const float4*)(src + 4);
            uint4 o;
            o.x = pk2(v0.x, v0.y); o.y = pk2(v0.z, v0.w);
            o.z = pk2(v1.x, v1.y); o.w = pk2(v1.z, v1.w);
            stage4[tid] = o;
        }
        {
            const uint4* srcw = wnb_g + (size_t)kt2 * 2048;
            ws4l[tid]        = srcw[tid];
            ws4l[512 + tid]  = srcw[512 + tid];
            ws4l[1024 + tid] = srcw[1024 + tid];
            ws4l[1536 + tid] = srcw[1536 + tid];
        }
        __syncthreads();
        #pragma unroll
        for (int kti = 0; kti < 2; ++kti) {
            short8 bA = *(const short8*)&w_s[((kti * 16 + wid * 2 + 0) * 64 + lane) * 8];
            short8 bB = *(const short8*)&w_s[((kti * 16 + wid * 2 + 1) * 64 + lane) * 8];
            #pragma unroll
            for (int mt = 0; mt < 4; ++mt) {
                short8 a = *(const short8*)&stage_s[((mt * 2 + kti) * 64 + lane) * 8];
                acc[mt][0] = __builtin_amdgcn_mfma_f32_16x16x32_bf16(a, bA, acc[mt][0], 0, 0, 0);
                acc[mt][1] = __builtin_amdgcn_mfma_f32_16x16x32_bf16(a, bB, acc[mt][1], 0, 0, 0);
            }
        }
        __syncthreads();
    }

    // =================== epilogue: gate + row reduction ===================
    // C-frag: local row = mt*16 + (lane>>4)*4 + r ; col = wid*32 + nt*16 + (lane&15)
    #pragma unroll
    for (int nd = 0; nd < 2; ++nd) {
        int node = blockIdx.x * 2 + nd;
        #pragma unroll
        for (int nt = 0; nt < 2; ++nt) {
            int col = wid * 32 + nt * 16 + (lane & 15);
            float bn = bnb[col];
            float s = 0.f;
            #pragma unroll
            for (int m2 = 0; m2 < 2; ++m2) {
                int mt = nd * 2 + m2;
                int base = (((wid * 2 + nt) * 4 + mt) * 64 + lane) * 2;
                unsigned int p01 = phi_s[base], p23 = phi_s[base + 1];
                float ph0 = __uint_as_float(p01 << 16);
                float ph1 = __uint_as_float(p01 & 0xffff0000u);
                float ph2 = __uint_as_float(p23 << 16);
                float ph3 = __uint_as_float(p23 & 0xffff0000u);
                s += ph0 * (acc[mt][nt][0] + bn) + ph1 * (acc[mt][nt][1] + bn)
                   + ph2 * (acc[mt][nt][2] + bn) + ph3 * (acc[mt][nt][3] + bn);
            }
            s += __shfl_xor(s, 16);
            s += __shfl_xor(s, 32);
            if (lane < 16) msg_out[(size_t)node * 256 + col] = s;
        }
    }
}

// ---------------------------------------------------------------------------
// Kernel 3: out = silu(h_center @ Wc + bc + msg), msg lives in `out` already.
// 256 threads = 4 waves (col quarters), 64 rows per block.
// ---------------------------------------------------------------------------
__global__ __launch_bounds__(256) void out_kernel(
        const float* __restrict__ hc,     // [N,256]
        const float* __restrict__ bc,     // [256]
        const uint4* __restrict__ wc_g,   // frag bf16, 8192 uint4
        float* __restrict__ out)          // [N,256], contains msg on entry
{
    __shared__ unsigned short a_s[4 * 2 * 64 * 8];    // 8KB
    __shared__ unsigned short wc_s[2 * 16 * 64 * 8];  // 32KB

    const int tid  = threadIdx.x;
    const int lane = tid & 63;
    const int wn   = tid >> 6;        // 0..3
    const int rblk = blockIdx.x * 64;

    f32x4 acc[4][4];
    #pragma unroll
    for (int mt = 0; mt < 4; ++mt)
        #pragma unroll
        for (int nt = 0; nt < 4; ++nt)
            acc[mt][nt] = (f32x4){0.f, 0.f, 0.f, 0.f};

    uint4* af4 = (uint4*)a_s;
    for (int kt2 = 0; kt2 < 4; ++kt2) {
        {
            int row = tid >> 2, quarter = tid & 3;
            const float* src = hc + (size_t)(rblk + row) * 256 + kt2 * 64 + quarter * 16;
            float4 v0 = *(const float4*)(src + 0);
            float4 v1 = *(const float4*)(src + 4);
            float4 v2 = *(const float4*)(src + 8);
            float4 v3 = *(const float4*)(src + 12);
            uint4 p0, p1;
            p0.x = pk2(v0.x, v0.y); p0.y = pk2(v0.z, v0.w);
            p0.z = pk2(v1.x, v1.y); p0.w = pk2(v1.z, v1.w);
            p1.x = pk2(v2.x, v2.y); p1.y = pk2(v2.z, v2.w);
            p1.z = pk2(v3.x, v3.y); p1.w = pk2(v3.z, v3.w);
            int mt = row >> 4, kti = quarter >> 1, fr = row & 15;
            int g0 = (quarter & 1) * 2;
            af4[(mt * 2 + kti) * 64 + g0 * 16 + fr]       = p0;
            af4[(mt * 2 + kti) * 64 + (g0 + 1) * 16 + fr] = p1;
            const uint4* srcw = wc_g + kt2 * 2048;
            uint4* dw = (uint4*)wc_s;
            #pragma unroll
            for (int j = 0; j < 8; ++j)
                dw[j * 256 + tid] = srcw[j * 256 + tid];
        }
        __syncthreads();
        #pragma unroll
        for (int kti = 0; kti < 2; ++kti) {
            short8 b[4];
            #pragma unroll
            for (int nt = 0; nt < 4; ++nt)
                b[nt] = *(const short8*)&wc_s[((kti * 16 + wn * 4 + nt) * 64 + lane) * 8];
            #pragma unroll
            for (int mt = 0; mt < 4; ++mt) {
                short8 a = *(const short8*)&a_s[((mt * 2 + kti) * 64 + lane) * 8];
                #pragma unroll
                for (int nt = 0; nt < 4; ++nt)
                    acc[mt][nt] = __builtin_amdgcn_mfma_f32_16x16x32_bf16(a, b[nt], acc[mt][nt], 0, 0, 0);
            }
        }
        __syncthreads();
    }

    #pragma unroll
    for (int mt = 0; mt < 4; ++mt)
        #pragma unroll
        for (int nt = 0; nt < 4; ++nt)
            #pragma unroll
            for (int r = 0; r < 4; ++r) {
                int grow = rblk + mt * 16 + ((lane >> 4) << 2) + r;
                int col  = wn * 64 + nt * 16 + (lane & 15);
                size_t idx = (size_t)grow * 256 + col;
                float v = acc[mt][nt][r] + bc[col] + out[idx];
                out[idx] = silu_f(v);
            }
}

// ---------------------------------------------------------------------------
extern "C" void kernel_launch(void* const* d_in, const int* in_sizes, int n_in,
                              void* d_out, int out_size, void* d_ws, size_t ws_size,
                              hipStream_t stream) {
    const float* h_center    = (const float*)d_in[0];
    const float* h_neighbors = (const float*)d_in[1];
    const float* differences = (const float*)d_in[2];
    const float* W_f1        = (const float*)d_in[3];
    const float* b_f1        = (const float*)d_in[4];
    const float* W_f2        = (const float*)d_in[5];
    const float* b_f2        = (const float*)d_in[6];
    const float* W_nb        = (const float*)d_in[7];
    const float* b_nb        = (const float*)d_in[8];
    const float* W_c         = (const float*)d_in[9];
    const float* b_c         = (const float*)d_in[10];
    float* out = (float*)d_out;

    uint4* ws4 = (uint4*)d_ws;            // 24576 * 16B = 384KB of scratch
    const uint4* wf2_ws = ws4;            // [0, 8192)
    const uint4* wnb_ws = ws4 + 8192;     // [8192, 16384)
    const uint4* wc_ws  = ws4 + 16384;    // [16384, 24576)

    prep_weights<<<96, 256, 0, stream>>>(W_f2, W_nb, W_c, ws4);
    msg_kernel<<<NN / 2, 512, 0, stream>>>(h_neighbors, differences, W_f1, b_f1,
                                           b_f2, b_nb, wf2_ws, wnb_ws, out);
    out_kernel<<<NN / 64, 256, 0, stream>>>(h_center, b_c, wc_ws, out);
}